// Round 1
// baseline (475.933 us; speedup 1.0000x reference)
//
#include <hip/hip_runtime.h>
#include <math.h>
#include <stdint.h>

#define N_PTS 1024
#define K_POS 512
#define K_FPS 32

// One block (512 threads) per submap.
// Phase 1: key = (bits(dist_xy) << 32) | idx  -> bitonic sort ascending
//          == jax.lax.top_k(-dist) ordering (stable tie-break on idx).
// Phase 2: deterministic FPS over the 512 selected points, 32 picks,
//          argmax tie-break = lowest position (== np.argmax).
__global__ __launch_bounds__(512) void fps_kernel(
    const float* __restrict__ pos,
    float* __restrict__ out_idx)   // [B*K_FPS] indices stored as float
{
#pragma clang fp contract(off)
    const int b   = blockIdx.x;
    const int tid = threadIdx.x;

    __shared__ unsigned long long key[N_PTS];     // 8 KB
    __shared__ float psx[K_POS], psy[K_POS], psz[K_POS]; // 6 KB
    __shared__ int   sidx[K_POS];                 // 2 KB
    __shared__ unsigned long long wred[8];

    const float* pb = pos + (size_t)b * N_PTS * 3;

    // ---- distance keys (xy only), 2 points per thread ----
    for (int i = tid; i < N_PTS; i += 512) {
        float x = pb[i * 3 + 0];
        float y = pb[i * 3 + 1];
        float xx = x * x;
        float yy = y * y;
        float d  = sqrtf(xx + yy);   // HIP default sqrtf is IEEE-correct
        unsigned int bits = __float_as_uint(d);  // d >= 0 -> monotonic bits
        key[i] = ((unsigned long long)bits << 32) | (unsigned int)i;
    }
    __syncthreads();

    // ---- bitonic sort ascending over 1024 keys ----
    for (unsigned int k = 2; k <= N_PTS; k <<= 1) {
        for (unsigned int j = k >> 1; j > 0; j >>= 1) {
            for (unsigned int i = tid; i < N_PTS; i += 512) {
                unsigned int ixj = i ^ j;
                if (ixj > i) {
                    unsigned long long a = key[i];
                    unsigned long long c = key[ixj];
                    bool up = ((i & k) == 0);
                    if ((a > c) == up) { key[i] = c; key[ixj] = a; }
                }
            }
            __syncthreads();
        }
    }

    // ---- unpack first K_POS (all 512 threads participate) ----
    {
        unsigned long long kk = key[tid];
        int orig = (int)(unsigned int)(kk & 0xffffffffull);
        sidx[tid] = orig;
        float x = pb[orig * 3 + 0];
        float y = pb[orig * 3 + 1];
        float z = pb[orig * 3 + 2];
        psx[tid] = x; psy[tid] = y; psz[tid] = z;
    }
    __syncthreads();

    // ---- FPS ----
    const float px = psx[tid], py = psy[tid], pz = psz[tid];
    float wx = psx[0], wy = psy[0], wz = psz[0];
    float dx = px - wx, dy = py - wy, dz = pz - wz;
    float t0 = dx * dx;
    float t1 = dy * dy;
    float t2 = dz * dz;
    float mind = (t0 + t1) + t2;   // matches np sequential axis sum

    if (tid == 0) out_idx[(size_t)b * K_FPS + 0] = (float)sidx[0];

    const int lane = tid & 63;
    const int wave = tid >> 6;

    for (int it = 1; it < K_FPS; ++it) {
        // pack: larger mind wins; tie -> smaller tid (position)
        unsigned long long kk =
            ((unsigned long long)__float_as_uint(mind) << 32) |
            (unsigned long long)(0xffffffffu - (unsigned int)tid);
        #pragma unroll
        for (int off = 32; off > 0; off >>= 1) {
            unsigned long long o = __shfl_xor(kk, off, 64);
            if (o > kk) kk = o;
        }
        if (lane == 0) wred[wave] = kk;
        __syncthreads();
        unsigned long long best = wred[0];
        #pragma unroll
        for (int w = 1; w < 8; ++w) {
            unsigned long long o = wred[w];
            if (o > best) best = o;
        }
        int p = (int)(0xffffffffu - (unsigned int)(best & 0xffffffffull));
        if (tid == 0) out_idx[(size_t)b * K_FPS + it] = (float)sidx[p];
        wx = psx[p]; wy = psy[p]; wz = psz[p];
        dx = px - wx; dy = py - wy; dz = pz - wz;
        float u0 = dx * dx;
        float u1 = dy * dy;
        float u2 = dz * dz;
        float d2 = (u0 + u1) + u2;
        mind = fminf(mind, d2);
        __syncthreads();   // protect wred before next iteration's write
    }
}

// One thread per selected point: 32->16->8->1 MLP + softplus.
__global__ __launch_bounds__(256) void mlp_kernel(
    const float* __restrict__ x,
    const float* __restrict__ W1, const float* __restrict__ b1,
    const float* __restrict__ W2, const float* __restrict__ b2,
    const float* __restrict__ W3, const float* __restrict__ b3,
    const float* __restrict__ idx_f,   // [total] indices as float (0..1023)
    float* __restrict__ out_w, int total)
{
    __shared__ float sW1[32 * 16];
    __shared__ float sW2[16 * 8];
    __shared__ float sW3[8];
    __shared__ float sb1[16];
    __shared__ float sb2[8];
    __shared__ float sb3;

    for (int i = threadIdx.x; i < 512; i += 256) sW1[i] = W1[i];
    if (threadIdx.x < 128) sW2[threadIdx.x] = W2[threadIdx.x];
    if (threadIdx.x < 16)  sb1[threadIdx.x] = b1[threadIdx.x];
    if (threadIdx.x < 8) {
        sb2[threadIdx.x] = b2[threadIdx.x];
        sW3[threadIdx.x] = W3[threadIdx.x];
    }
    if (threadIdx.x == 0) sb3 = b3[0];
    __syncthreads();

    int t = blockIdx.x * 256 + threadIdx.x;
    if (t >= total) return;

    int b    = t >> 5;                       // submap
    int orig = (int)(idx_f[t] + 0.5f);       // exact for 0..1023
    const float* xr = x + ((size_t)b * N_PTS + (size_t)orig) * 32;

    float xi[32];
    #pragma unroll
    for (int i = 0; i < 32; i += 4) {
        float4 v = *(const float4*)(xr + i);
        xi[i] = v.x; xi[i + 1] = v.y; xi[i + 2] = v.z; xi[i + 3] = v.w;
    }

    float h1[16];
    #pragma unroll
    for (int j = 0; j < 16; ++j) {
        float a = sb1[j];
        #pragma unroll
        for (int i = 0; i < 32; ++i) a += xi[i] * sW1[i * 16 + j];
        h1[j] = fmaxf(a, 0.0f);
    }
    float h2[8];
    #pragma unroll
    for (int j = 0; j < 8; ++j) {
        float a = sb2[j];
        #pragma unroll
        for (int i = 0; i < 16; ++i) a += h1[i] * sW2[i * 8 + j];
        h2[j] = fmaxf(a, 0.0f);
    }
    float v = sb3;
    #pragma unroll
    for (int i = 0; i < 8; ++i) v += h2[i] * sW3[i];

    // softplus, overflow-safe: max(v,0) + log1p(exp(-|v|))
    float sp = fmaxf(v, 0.0f) + log1pf(expf(-fabsf(v)));
    out_w[t] = sp;
}

extern "C" void kernel_launch(void* const* d_in, const int* in_sizes, int n_in,
                              void* d_out, int out_size, void* d_ws, size_t ws_size,
                              hipStream_t stream) {
    const float* x   = (const float*)d_in[0];
    const float* pos = (const float*)d_in[1];
    // d_in[2] = batch (unused; defines B)
    const float* W1 = (const float*)d_in[3];
    const float* b1 = (const float*)d_in[4];
    const float* W2 = (const float*)d_in[5];
    const float* b2 = (const float*)d_in[6];
    const float* W3 = (const float*)d_in[7];
    const float* b3 = (const float*)d_in[8];

    const int B = in_sizes[2] / N_PTS;     // 2048
    float* out_w = (float*)d_out;                  // [B*K_FPS] weights
    float* out_i = (float*)d_out + (size_t)B * K_FPS; // [B*K_FPS] indices (as f32)

    fps_kernel<<<B, 512, 0, stream>>>(pos, out_i);

    const int total = B * K_FPS;
    mlp_kernel<<<(total + 255) / 256, 256, 0, stream>>>(
        x, W1, b1, W2, b2, W3, b3, out_i, out_w, total);
}

// Round 2
// 395.158 us; speedup vs baseline: 1.2044x; 1.2044x over previous
//
#include <hip/hip_runtime.h>
#include <math.h>
#include <stdint.h>

#define N_PTS 1024
#define K_POS 512
#define K_FPS 32

typedef unsigned long long u64;
typedef unsigned int u32;

__device__ __forceinline__ u64 shfl_xor_u64(u64 v, int mask) {
    return __shfl_xor(v, mask, 64);
}

// ---------------------------------------------------------------------------
// Kernel 1: per-submap bitonic sort of (dist_bits<<32 | idx), 512 thr/block,
// 2 keys/thread in registers. j<64 stages via shfl_xor (no barrier);
// j in {64,128,256} via LDS (9 stages); j=512 intra-thread.
// Writes sorted top-512 as float4{x,y,z,idx} to ws.
// ---------------------------------------------------------------------------
__global__ __launch_bounds__(512) void sort_kernel(
    const float* __restrict__ pos,
    float4* __restrict__ ws)
{
#pragma clang fp contract(off)
    const int b   = blockIdx.x;
    const int tid = threadIdx.x;
    __shared__ u64 key[N_PTS];   // 8 KB

    const float* pb = pos + (size_t)b * N_PTS * 3;

    u64 v0, v1;
    {
        float x = pb[tid * 3 + 0];
        float y = pb[tid * 3 + 1];
        float xx = x * x, yy = y * y;
        float d = sqrtf(xx + yy);                       // IEEE sqrt, matches np
        v0 = ((u64)__float_as_uint(d) << 32) | (u32)tid;
        int i = tid + 512;
        x = pb[i * 3 + 0];
        y = pb[i * 3 + 1];
        xx = x * x; yy = y * y;
        d = sqrtf(xx + yy);
        v1 = ((u64)__float_as_uint(d) << 32) | (u32)i;
    }

    const int i0 = tid, i1 = tid + 512;
    for (int k = 2; k <= N_PTS; k <<= 1) {
        const bool up0 = ((i0 & k) == 0);
        const bool up1 = ((i1 & k) == 0);
        for (int j = k >> 1; j > 0; j >>= 1) {
            if (j == 512) {
                // k==1024 only; pair (i0, i0+512), ascending
                u64 lo = (v0 < v1) ? v0 : v1;
                u64 hi = (v0 < v1) ? v1 : v0;
                v0 = lo; v1 = hi;
            } else if (j >= 64) {
                key[i0] = v0; key[i1] = v1;
                __syncthreads();
                u64 o0 = key[i0 ^ j];
                u64 o1 = key[i1 ^ j];
                bool keep0 = (((i0 & j) == 0) == up0);
                bool keep1 = (((i1 & j) == 0) == up1);
                v0 = ((v0 < o0) == keep0) ? v0 : o0;
                v1 = ((v1 < o1) == keep1) ? v1 : o1;
                __syncthreads();
            } else {
                u64 o0 = shfl_xor_u64(v0, j);
                u64 o1 = shfl_xor_u64(v1, j);
                bool keep0 = (((i0 & j) == 0) == up0);
                bool keep1 = (((i1 & j) == 0) == up1);
                v0 = ((v0 < o0) == keep0) ? v0 : o0;
                v1 = ((v1 < o1) == keep1) ? v1 : o1;
            }
        }
    }

    // v0 holds sorted rank `tid` (0..511): the K_POS closest points in order.
    int orig = (int)(u32)(v0 & 0xffffffffu);
    float x = pb[orig * 3 + 0];
    float y = pb[orig * 3 + 1];
    float z = pb[orig * 3 + 2];
    ws[(size_t)b * K_POS + tid] = make_float4(x, y, z, (float)orig);
}

// ---------------------------------------------------------------------------
// Kernel 2: barrier-free FPS, one wave (64 lanes) per submap, 8 pts/lane.
// Element e = r*64 + lane; tie-break = smallest e (== np.argmax first-max).
// ---------------------------------------------------------------------------
__global__ __launch_bounds__(256) void fps_wave_kernel(
    const float4* __restrict__ ws,
    float* __restrict__ out_idx,
    int B)
{
#pragma clang fp contract(off)
    const int lane = threadIdx.x & 63;
    const int b    = blockIdx.x * 4 + (threadIdx.x >> 6);
    if (b >= B) return;

    const float4* wsb = ws + (size_t)b * K_POS;
    float px[8], py[8], pz[8], pidx[8], mind[8];
    #pragma unroll
    for (int r = 0; r < 8; ++r) {
        float4 p = wsb[r * 64 + lane];
        px[r] = p.x; py[r] = p.y; pz[r] = p.z; pidx[r] = p.w;
    }

    float wx = __shfl(px[0], 0, 64);
    float wy = __shfl(py[0], 0, 64);
    float wz = __shfl(pz[0], 0, 64);
    float wi = __shfl(pidx[0], 0, 64);

    float* ob = out_idx + (size_t)b * K_FPS;
    if (lane == 0) ob[0] = wi;

    #pragma unroll
    for (int r = 0; r < 8; ++r) {
        float dx = px[r] - wx, dy = py[r] - wy, dz = pz[r] - wz;
        float u0 = dx * dx, u1 = dy * dy, u2 = dz * dz;
        mind[r] = (u0 + u1) + u2;      // np sequential axis sum
    }

    for (int it = 1; it < K_FPS; ++it) {
        u64 best = 0;
        #pragma unroll
        for (int r = 0; r < 8; ++r) {
            int e = r * 64 + lane;
            u64 kk = ((u64)__float_as_uint(mind[r]) << 32) |
                     (u64)(0xffffffffu - (u32)e);
            if (kk > best) best = kk;
        }
        #pragma unroll
        for (int off = 32; off > 0; off >>= 1) {
            u64 o = shfl_xor_u64(best, off);
            if (o > best) best = o;
        }
        int ew = (int)(0xffffffffu - (u32)(best & 0xffffffffu));
        int rw = ew >> 6, lw = ew & 63;
        float sx = 0.f, sy = 0.f, sz = 0.f, si = 0.f;
        #pragma unroll
        for (int r = 0; r < 8; ++r)
            if (r == rw) { sx = px[r]; sy = py[r]; sz = pz[r]; si = pidx[r]; }
        wx = __shfl(sx, lw, 64);
        wy = __shfl(sy, lw, 64);
        wz = __shfl(sz, lw, 64);
        wi = __shfl(si, lw, 64);
        if (lane == 0) ob[it] = wi;

        #pragma unroll
        for (int r = 0; r < 8; ++r) {
            float dx = px[r] - wx, dy = py[r] - wy, dz = pz[r] - wz;
            float u0 = dx * dx, u1 = dy * dy, u2 = dz * dz;
            float d2 = (u0 + u1) + u2;
            mind[r] = fminf(mind[r], d2);
        }
    }
}

// ---------------------------------------------------------------------------
// Kernel 3: MLP 32->16->8->1 + softplus at the 65536 selected points.
// ---------------------------------------------------------------------------
__global__ __launch_bounds__(256) void mlp_kernel(
    const float* __restrict__ x,
    const float* __restrict__ W1, const float* __restrict__ b1,
    const float* __restrict__ W2, const float* __restrict__ b2,
    const float* __restrict__ W3, const float* __restrict__ b3,
    const float* __restrict__ idx_f,
    float* __restrict__ out_w, int total)
{
    __shared__ float sW1[32 * 16];
    __shared__ float sW2[16 * 8];
    __shared__ float sW3[8];
    __shared__ float sb1[16];
    __shared__ float sb2[8];
    __shared__ float sb3;

    for (int i = threadIdx.x; i < 512; i += 256) sW1[i] = W1[i];
    if (threadIdx.x < 128) sW2[threadIdx.x] = W2[threadIdx.x];
    if (threadIdx.x < 16)  sb1[threadIdx.x] = b1[threadIdx.x];
    if (threadIdx.x < 8) {
        sb2[threadIdx.x] = b2[threadIdx.x];
        sW3[threadIdx.x] = W3[threadIdx.x];
    }
    if (threadIdx.x == 0) sb3 = b3[0];
    __syncthreads();

    int t = blockIdx.x * 256 + threadIdx.x;
    if (t >= total) return;

    int b    = t >> 5;
    int orig = (int)(idx_f[t] + 0.5f);
    const float* xr = x + ((size_t)b * N_PTS + (size_t)orig) * 32;

    float xi[32];
    #pragma unroll
    for (int i = 0; i < 32; i += 4) {
        float4 v = *(const float4*)(xr + i);
        xi[i] = v.x; xi[i + 1] = v.y; xi[i + 2] = v.z; xi[i + 3] = v.w;
    }

    float h1[16];
    #pragma unroll
    for (int j = 0; j < 16; ++j) {
        float a = sb1[j];
        #pragma unroll
        for (int i = 0; i < 32; ++i) a += xi[i] * sW1[i * 16 + j];
        h1[j] = fmaxf(a, 0.0f);
    }
    float h2[8];
    #pragma unroll
    for (int j = 0; j < 8; ++j) {
        float a = sb2[j];
        #pragma unroll
        for (int i = 0; i < 16; ++i) a += h1[i] * sW2[i * 8 + j];
        h2[j] = fmaxf(a, 0.0f);
    }
    float v = sb3;
    #pragma unroll
    for (int i = 0; i < 8; ++i) v += h2[i] * sW3[i];

    float sp = fmaxf(v, 0.0f) + log1pf(expf(-fabsf(v)));
    out_w[t] = sp;
}

extern "C" void kernel_launch(void* const* d_in, const int* in_sizes, int n_in,
                              void* d_out, int out_size, void* d_ws, size_t ws_size,
                              hipStream_t stream) {
    const float* x   = (const float*)d_in[0];
    const float* pos = (const float*)d_in[1];
    const float* W1 = (const float*)d_in[3];
    const float* b1 = (const float*)d_in[4];
    const float* W2 = (const float*)d_in[5];
    const float* b2 = (const float*)d_in[6];
    const float* W3 = (const float*)d_in[7];
    const float* b3 = (const float*)d_in[8];

    const int B = in_sizes[2] / N_PTS;              // 2048
    float* out_w = (float*)d_out;                   // [B*K_FPS]
    float* out_i = (float*)d_out + (size_t)B * K_FPS;
    float4* ws   = (float4*)d_ws;                   // B*K_POS float4 = 16 MB

    sort_kernel<<<B, 512, 0, stream>>>(pos, ws);
    fps_wave_kernel<<<(B + 3) / 4, 256, 0, stream>>>(ws, out_i, B);

    const int total = B * K_FPS;
    mlp_kernel<<<(total + 255) / 256, 256, 0, stream>>>(
        x, W1, b1, W2, b2, W3, b3, out_i, out_w, total);
}

// Round 3
// 392.796 us; speedup vs baseline: 1.2117x; 1.0060x over previous
//
#include <hip/hip_runtime.h>
#include <math.h>
#include <stdint.h>

#define N_PTS 1024
#define K_POS 512
#define K_FPS 32

typedef unsigned long long u64;
typedef unsigned int u32;

__device__ __forceinline__ u64 shfl_xor_u64(u64 v, int mask) {
    return __shfl_xor(v, mask, 64);
}

// One bitonic compare-exchange stage with j < 64 (cross-lane via shfl_xor).
// e = r*64 + lane; for j<64 the partner differs only in lane bits.
__device__ __forceinline__ void shuffle_stage(u64 key[16], int j, int k, int lane) {
    #pragma unroll
    for (int r = 0; r < 16; ++r) {
        int e = (r << 6) | lane;
        u64 o = shfl_xor_u64(key[r], j);
        bool up      = ((e & k) == 0);
        bool lowhalf = ((lane & j) == 0);       // j<64 -> e&j == lane&j
        bool keep = ((key[r] < o) == (lowhalf == up));
        key[r] = keep ? key[r] : o;
    }
}

// One bitonic stage with j >= 64 (partner differs only in r): pure register
// compare-swap. JR = j>>6, KR = k>>6 (k >= 128 here, so up depends on r only).
template<int JR, int KR>
__device__ __forceinline__ void intra_stage(u64 key[16]) {
    #pragma unroll
    for (int r = 0; r < 16; ++r) {
        if ((r & JR) == 0) {
            const int r2 = r | JR;
            const bool up = ((r & KR) == 0);
            u64 a = key[r], c = key[r2];
            u64 lo = (a < c) ? a : c;
            u64 hi = (a < c) ? c : a;
            key[r]  = up ? lo : hi;
            key[r2] = up ? hi : lo;
        }
    }
}

// ---------------------------------------------------------------------------
// Fused kernel: one wave per submap. 16 keys/lane register bitonic sort of
// (dist_bits<<32 | idx), then barrier-free FPS over the sorted top-512
// (8 pts/lane). Zero __syncthreads, zero workspace traffic.
// ---------------------------------------------------------------------------
__global__ __launch_bounds__(256) void sortfps_kernel(
    const float* __restrict__ pos,
    float* __restrict__ out_idx,
    int B)
{
#pragma clang fp contract(off)
    const int lane = threadIdx.x & 63;
    const int b    = blockIdx.x * 4 + (threadIdx.x >> 6);
    if (b >= B) return;

    const float* pb = pos + (size_t)b * N_PTS * 3;

    // ---- build keys ----
    u64 key[16];
    #pragma unroll
    for (int r = 0; r < 16; ++r) {
        int e = (r << 6) | lane;
        float x = pb[e * 3 + 0];
        float y = pb[e * 3 + 1];
        float xx = x * x, yy = y * y;
        float d = sqrtf(xx + yy);               // IEEE sqrt, matches np
        key[r] = ((u64)__float_as_uint(d) << 32) | (u32)e;
    }

    // ---- bitonic sort ascending over 1024 elements, e = r*64 + lane ----
    // k = 2..64: all stages have j < 64 (cross-lane only)
    for (int k = 2; k <= 64; k <<= 1)
        for (int j = k >> 1; j > 0; j >>= 1)
            shuffle_stage(key, j, k, lane);
    // k = 128
    intra_stage<1, 2>(key);
    for (int j = 32; j > 0; j >>= 1) shuffle_stage(key, j, 128, lane);
    // k = 256
    intra_stage<2, 4>(key);
    intra_stage<1, 4>(key);
    for (int j = 32; j > 0; j >>= 1) shuffle_stage(key, j, 256, lane);
    // k = 512
    intra_stage<4, 8>(key);
    intra_stage<2, 8>(key);
    intra_stage<1, 8>(key);
    for (int j = 32; j > 0; j >>= 1) shuffle_stage(key, j, 512, lane);
    // k = 1024
    intra_stage<8, 16>(key);
    intra_stage<4, 16>(key);
    intra_stage<2, 16>(key);
    intra_stage<1, 16>(key);
    for (int j = 32; j > 0; j >>= 1) shuffle_stage(key, j, 1024, lane);

    // key[0..7] now hold ranks e = r*64+lane in [0,512): the K_POS closest
    // points in (dist, idx)-ascending order == jax.lax.top_k(-dist) order.

    // ---- gather selected coords ----
    float px[8], py[8], pz[8], pidx[8], mind[8];
    #pragma unroll
    for (int r = 0; r < 8; ++r) {
        int orig = (int)(u32)(key[r] & 0xffffffffu);
        px[r] = pb[orig * 3 + 0];
        py[r] = pb[orig * 3 + 1];
        pz[r] = pb[orig * 3 + 2];
        pidx[r] = (float)orig;
    }

    // ---- FPS (identical math/tie-break to validated round-2 kernel) ----
    float wx = __shfl(px[0], 0, 64);
    float wy = __shfl(py[0], 0, 64);
    float wz = __shfl(pz[0], 0, 64);
    float wi = __shfl(pidx[0], 0, 64);

    float* ob = out_idx + (size_t)b * K_FPS;
    if (lane == 0) ob[0] = wi;

    #pragma unroll
    for (int r = 0; r < 8; ++r) {
        float dx = px[r] - wx, dy = py[r] - wy, dz = pz[r] - wz;
        float u0 = dx * dx, u1 = dy * dy, u2 = dz * dz;
        mind[r] = (u0 + u1) + u2;               // np sequential axis sum
    }

    for (int it = 1; it < K_FPS; ++it) {
        u64 best = 0;
        #pragma unroll
        for (int r = 0; r < 8; ++r) {
            int e = r * 64 + lane;
            u64 kk = ((u64)__float_as_uint(mind[r]) << 32) |
                     (u64)(0xffffffffu - (u32)e);
            if (kk > best) best = kk;
        }
        #pragma unroll
        for (int off = 32; off > 0; off >>= 1) {
            u64 o = shfl_xor_u64(best, off);
            if (o > best) best = o;
        }
        int ew = (int)(0xffffffffu - (u32)(best & 0xffffffffu));
        int rw = ew >> 6, lw = ew & 63;
        float sx = 0.f, sy = 0.f, sz = 0.f, si = 0.f;
        #pragma unroll
        for (int r = 0; r < 8; ++r)
            if (r == rw) { sx = px[r]; sy = py[r]; sz = pz[r]; si = pidx[r]; }
        wx = __shfl(sx, lw, 64);
        wy = __shfl(sy, lw, 64);
        wz = __shfl(sz, lw, 64);
        wi = __shfl(si, lw, 64);
        if (lane == 0) ob[it] = wi;

        #pragma unroll
        for (int r = 0; r < 8; ++r) {
            float dx = px[r] - wx, dy = py[r] - wy, dz = pz[r] - wz;
            float u0 = dx * dx, u1 = dy * dy, u2 = dz * dz;
            float d2 = (u0 + u1) + u2;
            mind[r] = fminf(mind[r], d2);
        }
    }
}

// ---------------------------------------------------------------------------
// MLP 32->16->8->1 + softplus at the 65536 selected points.
// ---------------------------------------------------------------------------
__global__ __launch_bounds__(256) void mlp_kernel(
    const float* __restrict__ x,
    const float* __restrict__ W1, const float* __restrict__ b1,
    const float* __restrict__ W2, const float* __restrict__ b2,
    const float* __restrict__ W3, const float* __restrict__ b3,
    const float* __restrict__ idx_f,
    float* __restrict__ out_w, int total)
{
    __shared__ float sW1[32 * 16];
    __shared__ float sW2[16 * 8];
    __shared__ float sW3[8];
    __shared__ float sb1[16];
    __shared__ float sb2[8];
    __shared__ float sb3;

    for (int i = threadIdx.x; i < 512; i += 256) sW1[i] = W1[i];
    if (threadIdx.x < 128) sW2[threadIdx.x] = W2[threadIdx.x];
    if (threadIdx.x < 16)  sb1[threadIdx.x] = b1[threadIdx.x];
    if (threadIdx.x < 8) {
        sb2[threadIdx.x] = b2[threadIdx.x];
        sW3[threadIdx.x] = W3[threadIdx.x];
    }
    if (threadIdx.x == 0) sb3 = b3[0];
    __syncthreads();

    int t = blockIdx.x * 256 + threadIdx.x;
    if (t >= total) return;

    int b    = t >> 5;
    int orig = (int)(idx_f[t] + 0.5f);
    const float* xr = x + ((size_t)b * N_PTS + (size_t)orig) * 32;

    float xi[32];
    #pragma unroll
    for (int i = 0; i < 32; i += 4) {
        float4 v = *(const float4*)(xr + i);
        xi[i] = v.x; xi[i + 1] = v.y; xi[i + 2] = v.z; xi[i + 3] = v.w;
    }

    float h1[16];
    #pragma unroll
    for (int j = 0; j < 16; ++j) {
        float a = sb1[j];
        #pragma unroll
        for (int i = 0; i < 32; ++i) a += xi[i] * sW1[i * 16 + j];
        h1[j] = fmaxf(a, 0.0f);
    }
    float h2[8];
    #pragma unroll
    for (int j = 0; j < 8; ++j) {
        float a = sb2[j];
        #pragma unroll
        for (int i = 0; i < 16; ++i) a += h1[i] * sW2[i * 8 + j];
        h2[j] = fmaxf(a, 0.0f);
    }
    float v = sb3;
    #pragma unroll
    for (int i = 0; i < 8; ++i) v += h2[i] * sW3[i];

    float sp = fmaxf(v, 0.0f) + log1pf(expf(-fabsf(v)));
    out_w[t] = sp;
}

extern "C" void kernel_launch(void* const* d_in, const int* in_sizes, int n_in,
                              void* d_out, int out_size, void* d_ws, size_t ws_size,
                              hipStream_t stream) {
    const float* x   = (const float*)d_in[0];
    const float* pos = (const float*)d_in[1];
    const float* W1 = (const float*)d_in[3];
    const float* b1 = (const float*)d_in[4];
    const float* W2 = (const float*)d_in[5];
    const float* b2 = (const float*)d_in[6];
    const float* W3 = (const float*)d_in[7];
    const float* b3 = (const float*)d_in[8];

    const int B = in_sizes[2] / N_PTS;              // 2048
    float* out_w = (float*)d_out;                   // [B*K_FPS]
    float* out_i = (float*)d_out + (size_t)B * K_FPS;

    sortfps_kernel<<<(B + 3) / 4, 256, 0, stream>>>(pos, out_i, B);

    const int total = B * K_FPS;
    mlp_kernel<<<(total + 255) / 256, 256, 0, stream>>>(
        x, W1, b1, W2, b2, W3, b3, out_i, out_w, total);
}

// Round 4
// 386.603 us; speedup vs baseline: 1.2311x; 1.0160x over previous
//
#include <hip/hip_runtime.h>
#include <math.h>
#include <stdint.h>

#define N_PTS 1024
#define K_POS 512
#define K_FPS 32

typedef unsigned long long u64;
typedef unsigned int u32;

__device__ __forceinline__ u64 shfl_xor_u64(u64 v, int mask) {
    return __shfl_xor(v, mask, 64);
}

// Element mapping: p = lane*16 + r  (register bits = 4 low bits of p).
// Intra-lane bitonic stage, j in {1,2,4,8} (static), k runtime.
template<int J>
__device__ __forceinline__ void intra_stage(u64 key[16], int lane, int k) {
    #pragma unroll
    for (int r = 0; r < 16; ++r) {
        if ((r & J) == 0) {
            const int r2 = r | J;
            int p = (lane << 4) | r;
            bool up = ((p & k) == 0);
            u64 a = key[r], c = key[r2];
            bool sw = a < c;
            u64 lo = sw ? a : c;
            u64 hi = sw ? c : a;
            key[r]  = up ? lo : hi;
            key[r2] = up ? hi : lo;
        }
    }
}

// Cross-lane stage, j >= 16 (lane-xor m = j>>4), k >= 32 (up uniform per lane).
__device__ __forceinline__ void cross_stage(u64 key[16], int lane, int m, int k) {
    bool low = ((lane & m) == 0);
    bool up  = ((lane & (k >> 4)) == 0);
    bool sel = (low == up);
    #pragma unroll
    for (int r = 0; r < 16; ++r) {
        u64 o = shfl_xor_u64(key[r], m);
        key[r] = ((key[r] < o) == sel) ? key[r] : o;
    }
}

// ---------------------------------------------------------------------------
// Fused kernel: one wave per submap, p = lane*16 + r element mapping.
// 21 cross-lane stages (bpermute) + 34 register stages (VALU).
// After sort, ranks 0..511 reside in lanes 0..31 (16 per lane); FPS runs
// there with a 5-step value-only butterfly + ballot/ffs/readlane broadcast.
// ---------------------------------------------------------------------------
__global__ __launch_bounds__(256) void sortfps_kernel(
    const float* __restrict__ pos,
    float* __restrict__ out_idx,
    int B)
{
#pragma clang fp contract(off)
    const int lane = threadIdx.x & 63;
    const int sub  = threadIdx.x >> 6;
    const int b    = blockIdx.x * 4 + sub;

    __shared__ float spts[4][N_PTS * 3];   // 48 KB: xyz of all 1024 pts/submap

    if (b >= B) return;

    const float* pb = pos + (size_t)b * N_PTS * 3;

    // ---- load 16 contiguous points/lane (192 B), stage to LDS ----
    float4 f4[12];
    {
        const float4* pb4 = (const float4*)pb + (size_t)lane * 12;
        #pragma unroll
        for (int i = 0; i < 12; ++i) f4[i] = pb4[i];
        float4* sp4 = (float4*)&spts[sub][0] + lane * 12;
        #pragma unroll
        for (int i = 0; i < 12; ++i) sp4[i] = f4[i];
    }
    const float* f = (const float*)&f4[0];

    // ---- build keys: (bits(sqrt(x^2+y^2)) << 32) | p ----
    u64 key[16];
    #pragma unroll
    for (int r = 0; r < 16; ++r) {
        int p = (lane << 4) | r;
        float x = f[r * 3 + 0];
        float y = f[r * 3 + 1];
        float xx = x * x, yy = y * y;
        float d = sqrtf(xx + yy);          // IEEE sqrt, matches np
        key[r] = ((u64)__float_as_uint(d) << 32) | (u32)p;
    }

    // ---- bitonic sort ascending over 1024 elements ----
    // k = 2..16: all stages intra-lane (static j)
    intra_stage<1>(key, lane, 2);
    intra_stage<2>(key, lane, 4);
    intra_stage<1>(key, lane, 4);
    intra_stage<4>(key, lane, 8);
    intra_stage<2>(key, lane, 8);
    intra_stage<1>(key, lane, 8);
    intra_stage<8>(key, lane, 16);
    intra_stage<4>(key, lane, 16);
    intra_stage<2>(key, lane, 16);
    intra_stage<1>(key, lane, 16);
    // k = 32..1024: cross stages (j>=16) then intra tail (j=8..1)
    #pragma unroll 1
    for (int k = 32; k <= N_PTS; k <<= 1) {
        #pragma unroll 1
        for (int j = k >> 1; j >= 16; j >>= 1)
            cross_stage(key, lane, j >> 4, k);
        intra_stage<8>(key, lane, k);
        intra_stage<4>(key, lane, k);
        intra_stage<2>(key, lane, k);
        intra_stage<1>(key, lane, k);
    }

    // Ranks 0..511 (== jax.lax.top_k(-dist) order) are lanes 0..31, r 0..15.

    // ---- gather selected coords from LDS ----
    float px[16], py[16], pz[16], pidx[16], mind[16];
    #pragma unroll
    for (int r = 0; r < 16; ++r) {
        int orig = (int)(u32)(key[r] & 0xffffffffu);
        const float* sp = &spts[sub][orig * 3];
        px[r] = sp[0]; py[r] = sp[1]; pz[r] = sp[2];
        pidx[r] = (float)orig;
    }

    // ---- FPS ----
    float* ob = out_idx + (size_t)b * K_FPS;
    // winner 0 = rank 0 = lane 0, r 0
    float wx = __uint_as_float(__builtin_amdgcn_readlane(__float_as_uint(px[0]), 0));
    float wy = __uint_as_float(__builtin_amdgcn_readlane(__float_as_uint(py[0]), 0));
    float wz = __uint_as_float(__builtin_amdgcn_readlane(__float_as_uint(pz[0]), 0));
    if (lane == 0) ob[0] = pidx[0];

    #pragma unroll
    for (int r = 0; r < 16; ++r) {
        float dx = px[r] - wx, dy = py[r] - wy, dz = pz[r] - wz;
        float u0 = dx * dx, u1 = dy * dy, u2 = dz * dz;
        mind[r] = (u0 + u1) + u2;          // np sequential axis sum
    }
    if (lane >= 32) {
        #pragma unroll
        for (int r = 0; r < 16; ++r) mind[r] = -INFINITY;
    }

    for (int it = 1; it < K_FPS; ++it) {
        // local lexicographic-first max over r (strict > keeps smallest r)
        float bv = mind[0], bx = px[0], by = py[0], bz = pz[0], bi = pidx[0];
        #pragma unroll
        for (int r = 1; r < 16; ++r) {
            bool g = mind[r] > bv;
            bv = g ? mind[r] : bv;
            bx = g ? px[r] : bx;
            by = g ? py[r] : by;
            bz = g ? pz[r] : bz;
            bi = g ? pidx[r] : bi;
        }
        // value butterfly over lanes 0..31, bit-exact via signed-int compare
        // (valid: all values are nonneg floats or -inf)
        int bvi = __float_as_int(bv);
        int g = bvi;
        #pragma unroll
        for (int m = 1; m <= 16; m <<= 1) {
            int o = __shfl_xor(g, m, 64);
            g = (o > g) ? o : g;
        }
        u64 mask = __ballot(bvi == g) & 0xffffffffull;
        int W = __ffsll((unsigned long long)mask) - 1;  // smallest lane = smallest rank
        wx = __uint_as_float(__builtin_amdgcn_readlane(__float_as_uint(bx), W));
        wy = __uint_as_float(__builtin_amdgcn_readlane(__float_as_uint(by), W));
        wz = __uint_as_float(__builtin_amdgcn_readlane(__float_as_uint(bz), W));
        float wi = __uint_as_float(__builtin_amdgcn_readlane(__float_as_uint(bi), W));
        if (lane == 0) ob[it] = wi;

        #pragma unroll
        for (int r = 0; r < 16; ++r) {
            float dx = px[r] - wx, dy = py[r] - wy, dz = pz[r] - wz;
            float u0 = dx * dx, u1 = dy * dy, u2 = dz * dz;
            float d2 = (u0 + u1) + u2;
            mind[r] = fminf(mind[r], d2);   // fminf(-inf, x) = -inf for lanes>=32
        }
    }
}

// ---------------------------------------------------------------------------
// MLP 32->16->8->1 + softplus at the 65536 selected points.
// ---------------------------------------------------------------------------
__global__ __launch_bounds__(256) void mlp_kernel(
    const float* __restrict__ x,
    const float* __restrict__ W1, const float* __restrict__ b1,
    const float* __restrict__ W2, const float* __restrict__ b2,
    const float* __restrict__ W3, const float* __restrict__ b3,
    const float* __restrict__ idx_f,
    float* __restrict__ out_w, int total)
{
    __shared__ float sW1[32 * 16];
    __shared__ float sW2[16 * 8];
    __shared__ float sW3[8];
    __shared__ float sb1[16];
    __shared__ float sb2[8];
    __shared__ float sb3;

    for (int i = threadIdx.x; i < 512; i += 256) sW1[i] = W1[i];
    if (threadIdx.x < 128) sW2[threadIdx.x] = W2[threadIdx.x];
    if (threadIdx.x < 16)  sb1[threadIdx.x] = b1[threadIdx.x];
    if (threadIdx.x < 8) {
        sb2[threadIdx.x] = b2[threadIdx.x];
        sW3[threadIdx.x] = W3[threadIdx.x];
    }
    if (threadIdx.x == 0) sb3 = b3[0];
    __syncthreads();

    int t = blockIdx.x * 256 + threadIdx.x;
    if (t >= total) return;

    int b    = t >> 5;
    int orig = (int)(idx_f[t] + 0.5f);
    const float* xr = x + ((size_t)b * N_PTS + (size_t)orig) * 32;

    float xi[32];
    #pragma unroll
    for (int i = 0; i < 32; i += 4) {
        float4 v = *(const float4*)(xr + i);
        xi[i] = v.x; xi[i + 1] = v.y; xi[i + 2] = v.z; xi[i + 3] = v.w;
    }

    float h1[16];
    #pragma unroll
    for (int j = 0; j < 16; ++j) {
        float a = sb1[j];
        #pragma unroll
        for (int i = 0; i < 32; ++i) a += xi[i] * sW1[i * 16 + j];
        h1[j] = fmaxf(a, 0.0f);
    }
    float h2[8];
    #pragma unroll
    for (int j = 0; j < 8; ++j) {
        float a = sb2[j];
        #pragma unroll
        for (int i = 0; i < 16; ++i) a += h1[i] * sW2[i * 8 + j];
        h2[j] = fmaxf(a, 0.0f);
    }
    float v = sb3;
    #pragma unroll
    for (int i = 0; i < 8; ++i) v += h2[i] * sW3[i];

    float sp = fmaxf(v, 0.0f) + log1pf(expf(-fabsf(v)));
    out_w[t] = sp;
}

extern "C" void kernel_launch(void* const* d_in, const int* in_sizes, int n_in,
                              void* d_out, int out_size, void* d_ws, size_t ws_size,
                              hipStream_t stream) {
    const float* x   = (const float*)d_in[0];
    const float* pos = (const float*)d_in[1];
    const float* W1 = (const float*)d_in[3];
    const float* b1 = (const float*)d_in[4];
    const float* W2 = (const float*)d_in[5];
    const float* b2 = (const float*)d_in[6];
    const float* W3 = (const float*)d_in[7];
    const float* b3 = (const float*)d_in[8];

    const int B = in_sizes[2] / N_PTS;              // 2048
    float* out_w = (float*)d_out;                   // [B*K_FPS]
    float* out_i = (float*)d_out + (size_t)B * K_FPS;

    sortfps_kernel<<<(B + 3) / 4, 256, 0, stream>>>(pos, out_i, B);

    const int total = B * K_FPS;
    mlp_kernel<<<(total + 255) / 256, 256, 0, stream>>>(
        x, W1, b1, W2, b2, W3, b3, out_i, out_w, total);
}